// Round 4
// baseline (101.471 us; speedup 1.0000x reference)
//
#include <hip/hip_runtime.h>
#include <math.h>

#define B_   256
#define IN_  512
#define OUT_ 512
#define E_   256
#define DELTA_ 0.1f
#define LN_EPS_ 1e-5f

// ---------------------------------------------------------------------------
// K1: scores[i][o] = pred_emb[i,:]·attn_w[o,:] + attn_b[o]; row-LN over o;
//     sigmoid; wv[i][o] = (W[o][i], |W[o][i]|*sig[i][o]).
// 512 threads, 4 i-rows per block, grid 128. Each thread owns one o for all
// 4 rows -> attn_w float4 reused 4x in regs; attn_w L2 traffic 67 MB.
// ---------------------------------------------------------------------------
__global__ __launch_bounds__(512)
void k1_scores_ln_sig(const float* __restrict__ pred_emb,
                      const float* __restrict__ attn_w,
                      const float* __restrict__ attn_b,
                      const float* __restrict__ ln_g,
                      const float* __restrict__ ln_b,
                      const float* __restrict__ weights,
                      float2* __restrict__ wv) {
    __shared__ float pe[4][E_];        // 4 KB
    __shared__ float red[8][4][2];     // [wave][row][{s1,s2}]
    __shared__ float smu[4], srs[4];

    const int t    = threadIdx.x;      // 0..511
    const int lane = t & 63;
    const int wid  = t >> 6;           // 0..7
    const int i0   = blockIdx.x * 4;
    const int o    = t;

    // stage 4 pred_emb rows: 512 threads load 1024 floats
    #pragma unroll
    for (int k = 0; k < 2; ++k) {
        int p = t + 512 * k;
        pe[p >> 8][p & 255] = pred_emb[(size_t)(i0 + (p >> 8)) * E_ + (p & 255)];
    }
    __syncthreads();

    const float4* p0 = reinterpret_cast<const float4*>(pe[0]);
    const float4* p1 = reinterpret_cast<const float4*>(pe[1]);
    const float4* p2 = reinterpret_cast<const float4*>(pe[2]);
    const float4* p3 = reinterpret_cast<const float4*>(pe[3]);
    const float4* wrow = reinterpret_cast<const float4*>(attn_w + (size_t)o * E_);

    float a0 = 0.f, a1 = 0.f, a2 = 0.f, a3 = 0.f;
    #pragma unroll 8
    for (int e4 = 0; e4 < E_ / 4; ++e4) {
        float4 w4 = wrow[e4];
        float4 q0 = p0[e4];
        float4 q1 = p1[e4];
        float4 q2 = p2[e4];
        float4 q3 = p3[e4];
        a0 += q0.x * w4.x + q0.y * w4.y + q0.z * w4.z + q0.w * w4.w;
        a1 += q1.x * w4.x + q1.y * w4.y + q1.z * w4.z + q1.w * w4.w;
        a2 += q2.x * w4.x + q2.y * w4.y + q2.z * w4.z + q2.w * w4.w;
        a3 += q3.x * w4.x + q3.y * w4.y + q3.z * w4.z + q3.w * w4.w;
    }
    const float bo = attn_b[o];
    a0 += bo; a1 += bo; a2 += bo; a3 += bo;

    // LN stats per row over 512 o-values (one per thread)
    {
        float s10 = a0, s20 = a0 * a0;
        float s11 = a1, s21 = a1 * a1;
        float s12 = a2, s22 = a2 * a2;
        float s13 = a3, s23 = a3 * a3;
        #pragma unroll
        for (int off = 32; off > 0; off >>= 1) {
            s10 += __shfl_down(s10, off); s20 += __shfl_down(s20, off);
            s11 += __shfl_down(s11, off); s21 += __shfl_down(s21, off);
            s12 += __shfl_down(s12, off); s22 += __shfl_down(s22, off);
            s13 += __shfl_down(s13, off); s23 += __shfl_down(s23, off);
        }
        if (lane == 0) {
            red[wid][0][0] = s10; red[wid][0][1] = s20;
            red[wid][1][0] = s11; red[wid][1][1] = s21;
            red[wid][2][0] = s12; red[wid][2][1] = s22;
            red[wid][3][0] = s13; red[wid][3][1] = s23;
        }
    }
    __syncthreads();
    if (t < 4) {
        float s1 = 0.f, s2 = 0.f;
        #pragma unroll
        for (int w = 0; w < 8; ++w) { s1 += red[w][t][0]; s2 += red[w][t][1]; }
        float mu  = s1 / (float)OUT_;
        float var = s2 / (float)OUT_ - mu * mu;
        smu[t] = mu;
        srs[t] = rsqrtf(var + LN_EPS_);
    }
    __syncthreads();

    const float g  = ln_g[o];
    const float bb = ln_b[o];
    float z0 = (a0 - smu[0]) * srs[0] * g + bb;
    float z1 = (a1 - smu[1]) * srs[1] * g + bb;
    float z2 = (a2 - smu[2]) * srs[2] * g + bb;
    float z3 = (a3 - smu[3]) * srs[3] * g + bb;
    float sg0 = 1.f / (1.f + expf(-z0));
    float sg1 = 1.f / (1.f + expf(-z1));
    float sg2 = 1.f / (1.f + expf(-z2));
    float sg3 = 1.f / (1.f + expf(-z3));

    // adjacent i -> one float4 load of weights[o][i0..i0+3]
    float4 w4 = *reinterpret_cast<const float4*>(weights + (size_t)o * IN_ + i0);
    wv[(size_t)(i0 + 0) * OUT_ + o] = make_float2(w4.x, fabsf(w4.x) * sg0);
    wv[(size_t)(i0 + 1) * OUT_ + o] = make_float2(w4.y, fabsf(w4.y) * sg1);
    wv[(size_t)(i0 + 2) * OUT_ + o] = make_float2(w4.z, fabsf(w4.z) * sg2);
    wv[(size_t)(i0 + 3) * OUT_ + o] = make_float2(w4.w, fabsf(w4.w) * sg3);
}

// ---------------------------------------------------------------------------
// K2: split-K partials of dot = sum_i x*W, s = sum_i u*v, m = max_i u*v
//     (u = x*|x|), stored as lin = dot - DELTA*s and m.
// Tile: 64 b x 16 o; 256 thr = 16 o-lanes x 16 b-lanes, each b-lane owns
// 4 b-rows (bl, +16, +32, +48). Chunk 128 i, SK=4 -> grid (32,4,4)=512
// blocks, 2 blocks/CU (LDS 51 KB). Inner loop LDS+VALU only.
// xs rows padded to 33 float4; ws rows padded to 17 float2.
// (Round-0 config verbatim — best measured total, lowest partial traffic.)
// ---------------------------------------------------------------------------
#define K2_SK 4
#define K2_CH 128
#define K2_BO (B_ * OUT_)   // 131072

__global__ __launch_bounds__(256)
void k2_partials(const float* __restrict__ x,
                 const float2* __restrict__ wv,
                 float* __restrict__ plin,
                 float* __restrict__ pmax) {
    __shared__ float4 xs4[64 * 33];     // 33.8 KB
    __shared__ float2 ws2[K2_CH * 17];  // 17.4 KB

    const int t  = threadIdx.x;
    const int ot = t & 15;
    const int bl = t >> 4;              // 0..15
    const int o0 = blockIdx.x * 16;
    const int b0 = blockIdx.y * 64;
    const int sk = blockIdx.z;
    const int i0 = sk * K2_CH;

    // stage x tile (64 rows x 128 cols)
    #pragma unroll
    for (int k = 0; k < 8; ++k) {
        int p    = t + k * 256;         // 0..2047
        int row  = p >> 5;
        int col4 = p & 31;
        xs4[row * 33 + col4] = reinterpret_cast<const float4*>(
            x + (size_t)(b0 + row) * IN_ + i0)[col4];
    }
    // stage wv tile (128 rows x 16 cols)
    #pragma unroll
    for (int k = 0; k < 8; ++k) {
        int r = bl + 16 * k;
        ws2[r * 17 + ot] = wv[(size_t)(i0 + r) * OUT_ + o0 + ot];
    }
    __syncthreads();

    const int o = o0 + ot;
    float d0 = 0.f, s0 = 0.f, m0 = -INFINITY;
    float d1 = 0.f, s1 = 0.f, m1 = -INFINITY;
    float d2 = 0.f, s2 = 0.f, m2 = -INFINITY;
    float d3 = 0.f, s3 = 0.f, m3 = -INFINITY;

    #pragma unroll 2
    for (int i4 = 0; i4 < K2_CH / 4; ++i4) {
        float4 x0 = xs4[(bl +  0) * 33 + i4];
        float4 x1 = xs4[(bl + 16) * 33 + i4];
        float4 x2 = xs4[(bl + 32) * 33 + i4];
        float4 x3 = xs4[(bl + 48) * 33 + i4];
        float2 w0 = ws2[(4 * i4 + 0) * 17 + ot];
        float2 w1 = ws2[(4 * i4 + 1) * 17 + ot];
        float2 w2 = ws2[(4 * i4 + 2) * 17 + ot];
        float2 w3 = ws2[(4 * i4 + 3) * 17 + ot];
        float p;
        float4 u0 = make_float4(x0.x * fabsf(x0.x), x0.y * fabsf(x0.y),
                                x0.z * fabsf(x0.z), x0.w * fabsf(x0.w));
        float4 u1 = make_float4(x1.x * fabsf(x1.x), x1.y * fabsf(x1.y),
                                x1.z * fabsf(x1.z), x1.w * fabsf(x1.w));
        float4 u2 = make_float4(x2.x * fabsf(x2.x), x2.y * fabsf(x2.y),
                                x2.z * fabsf(x2.z), x2.w * fabsf(x2.w));
        float4 u3 = make_float4(x3.x * fabsf(x3.x), x3.y * fabsf(x3.y),
                                x3.z * fabsf(x3.z), x3.w * fabsf(x3.w));

        d0 = fmaf(x0.x, w0.x, d0); p = u0.x * w0.y; s0 += p; m0 = fmaxf(m0, p);
        d1 = fmaf(x1.x, w0.x, d1); p = u1.x * w0.y; s1 += p; m1 = fmaxf(m1, p);
        d2 = fmaf(x2.x, w0.x, d2); p = u2.x * w0.y; s2 += p; m2 = fmaxf(m2, p);
        d3 = fmaf(x3.x, w0.x, d3); p = u3.x * w0.y; s3 += p; m3 = fmaxf(m3, p);

        d0 = fmaf(x0.y, w1.x, d0); p = u0.y * w1.y; s0 += p; m0 = fmaxf(m0, p);
        d1 = fmaf(x1.y, w1.x, d1); p = u1.y * w1.y; s1 += p; m1 = fmaxf(m1, p);
        d2 = fmaf(x2.y, w1.x, d2); p = u2.y * w1.y; s2 += p; m2 = fmaxf(m2, p);
        d3 = fmaf(x3.y, w1.x, d3); p = u3.y * w1.y; s3 += p; m3 = fmaxf(m3, p);

        d0 = fmaf(x0.z, w2.x, d0); p = u0.z * w2.y; s0 += p; m0 = fmaxf(m0, p);
        d1 = fmaf(x1.z, w2.x, d1); p = u1.z * w2.y; s1 += p; m1 = fmaxf(m1, p);
        d2 = fmaf(x2.z, w2.x, d2); p = u2.z * w2.y; s2 += p; m2 = fmaxf(m2, p);
        d3 = fmaf(x3.z, w2.x, d3); p = u3.z * w2.y; s3 += p; m3 = fmaxf(m3, p);

        d0 = fmaf(x0.w, w3.x, d0); p = u0.w * w3.y; s0 += p; m0 = fmaxf(m0, p);
        d1 = fmaf(x1.w, w3.x, d1); p = u1.w * w3.y; s1 += p; m1 = fmaxf(m1, p);
        d2 = fmaf(x2.w, w3.x, d2); p = u2.w * w3.y; s2 += p; m2 = fmaxf(m2, p);
        d3 = fmaf(x3.w, w3.x, d3); p = u3.w * w3.y; s3 += p; m3 = fmaxf(m3, p);
    }

    const size_t base = (size_t)sk * K2_BO + (size_t)b0 * OUT_ + o;
    plin[base + (size_t)(bl +  0) * OUT_] = d0 - DELTA_ * s0;
    plin[base + (size_t)(bl + 16) * OUT_] = d1 - DELTA_ * s1;
    plin[base + (size_t)(bl + 32) * OUT_] = d2 - DELTA_ * s2;
    plin[base + (size_t)(bl + 48) * OUT_] = d3 - DELTA_ * s3;
    pmax[base + (size_t)(bl +  0) * OUT_] = m0;
    pmax[base + (size_t)(bl + 16) * OUT_] = m1;
    pmax[base + (size_t)(bl + 32) * OUT_] = m2;
    pmax[base + (size_t)(bl + 48) * OUT_] = m3;
}

// ---------------------------------------------------------------------------
// K3: combine split-K partials, float4-wide. out = sum lin + DELTA * max m.
// ---------------------------------------------------------------------------
__global__ __launch_bounds__(256)
void k3_combine(const float4* __restrict__ plin4,
                const float4* __restrict__ pmax4,
                float4* __restrict__ out4) {
    const int g = blockIdx.x * 256 + threadIdx.x;   // 0..32767
    const int Q = K2_BO / 4;                        // 32768
    float4 l0 = plin4[g], l1 = plin4[Q + g], l2 = plin4[2 * Q + g], l3 = plin4[3 * Q + g];
    float4 m0 = pmax4[g], m1 = pmax4[Q + g], m2 = pmax4[2 * Q + g], m3 = pmax4[3 * Q + g];
    float4 r;
    r.x = (l0.x + l1.x + l2.x + l3.x) + DELTA_ * fmaxf(fmaxf(m0.x, m1.x), fmaxf(m2.x, m3.x));
    r.y = (l0.y + l1.y + l2.y + l3.y) + DELTA_ * fmaxf(fmaxf(m0.y, m1.y), fmaxf(m2.y, m3.y));
    r.z = (l0.z + l1.z + l2.z + l3.z) + DELTA_ * fmaxf(fmaxf(m0.z, m1.z), fmaxf(m2.z, m3.z));
    r.w = (l0.w + l1.w + l2.w + l3.w) + DELTA_ * fmaxf(fmaxf(m0.w, m1.w), fmaxf(m2.w, m3.w));
    out4[g] = r;
}

// ---------------------------------------------------------------------------
extern "C" void kernel_launch(void* const* d_in, const int* in_sizes, int n_in,
                              void* d_out, int out_size, void* d_ws, size_t ws_size,
                              hipStream_t stream) {
    const float* x        = (const float*)d_in[0];
    const float* weights  = (const float*)d_in[1];
    const float* pred_emb = (const float*)d_in[2];
    const float* attn_w   = (const float*)d_in[3];
    const float* attn_b   = (const float*)d_in[4];
    const float* ln_g     = (const float*)d_in[5];
    const float* ln_b     = (const float*)d_in[6];

    // workspace layout: wv (2 MB) | plin (2 MB) | pmax (2 MB)
    float2* wv   = (float2*)d_ws;
    float*  plin = (float*)d_ws + 2 * (size_t)IN_ * OUT_;
    float*  pmax = plin + (size_t)K2_SK * K2_BO;

    k1_scores_ln_sig<<<IN_ / 4, 512, 0, stream>>>(
        pred_emb, attn_w, attn_b, ln_g, ln_b, weights, wv);

    k2_partials<<<dim3(OUT_ / 16, B_ / 64, K2_SK), 256, 0, stream>>>(
        x, wv, plin, pmax);

    k3_combine<<<K2_BO / 4 / 256, 256, 0, stream>>>(
        (const float4*)plin, (const float4*)pmax, (float4*)d_out);
}